// Round 13
// baseline (23.512 us; speedup 1.0000x reference)
//
#include <hip/hip_runtime.h>
#include <math.h>

#define B_ 32768
#define E_ 256
#define S_ 1024
#define EPS_COS 1e-8f
#define EPS_NORM 1e-12f

typedef float fx4 __attribute__((ext_vector_type(4)));

// ---------------- kernel A: reduce-only -----------------------------------
// 2048 blocks x 256 threads, 16 rows/block, one row per 16-lane group.
// 4 fx4 loads/lane (plain loads -> input lands in L3 for kernel B),
// 4-level butterfly, tiny scalar writes only (rowsum/sqsum/PB).
__global__ __launch_bounds__(256) void reduce_kernel(
        const float* __restrict__ x, const int* __restrict__ tgt,
        float* __restrict__ outL,
        float* __restrict__ rowsum, float* __restrict__ sqsum,
        float* __restrict__ PBsum, int* __restrict__ PBtgt) {
    __shared__ float sSum[16];
    __shared__ int   sTgt[16];

    int tid = threadIdx.x;
    int g   = tid >> 4;                 // 16 groups of 16 lanes
    int li  = tid & 15;
    int row = blockIdx.x * 16 + g;

    if (blockIdx.x == 0 && tid == 0) outL[0] = 0.f;

    const fx4* __restrict__ xr = (const fx4*)(x + (size_t)row * E_);

    fx4 a0 = xr[li];
    fx4 a1 = xr[li + 16];
    fx4 a2 = xr[li + 32];
    fx4 a3 = xr[li + 48];

    float sum = (a0.x + a0.y + a0.z + a0.w) + (a1.x + a1.y + a1.z + a1.w)
              + (a2.x + a2.y + a2.z + a2.w) + (a3.x + a3.y + a3.z + a3.w);
    float sq  = (a0.x*a0.x + a0.y*a0.y + a0.z*a0.z + a0.w*a0.w)
              + (a1.x*a1.x + a1.y*a1.y + a1.z*a1.z + a1.w*a1.w)
              + (a2.x*a2.x + a2.y*a2.y + a2.z*a2.z + a2.w*a2.w)
              + (a3.x*a3.x + a3.y*a3.y + a3.z*a3.z + a3.w*a3.w);

    #pragma unroll
    for (int o = 8; o >= 1; o >>= 1) {  // intra-16-lane only
        sum += __shfl_xor(sum, o, 64);
        sq  += __shfl_xor(sq,  o, 64);
    }

    if (li == 0) {
        rowsum[row] = sum;
        sqsum[row]  = sq;
        sSum[g] = sum;
        sTgt[g] = tgt[row];
    }
    __syncthreads();
    if (tid == 0) {
        float tot = 0.f;
        int t0 = sTgt[0];
        int same = 1;
        #pragma unroll
        for (int k = 0; k < 16; ++k) {
            tot += sSum[k];
            same &= (sTgt[k] == t0);
        }
        PBsum[blockIdx.x] = tot;
        PBtgt[blockIdx.x] = same ? t0 : -1;
    }
}

// ---------------- kernel B: scale-only (copy-shaped) -----------------------
// 2048 blocks x 256 threads, 16 rows/block. Wave w owns rows 16b+4w..+3;
// load/store instruction j covers ONE WHOLE ROW (64 lanes x 16B = 1 KB
// contiguous). rn is wave-uniform per row. No shfl, no LDS, no barriers.
__global__ __launch_bounds__(256) void scale_kernel(
        const float* __restrict__ x, const float* __restrict__ sqsum,
        float* __restrict__ outN) {
    int tid  = threadIdx.x;
    int w    = tid >> 6;                // wave in block
    int l    = tid & 63;
    int row0 = blockIdx.x * 16 + w * 4;

    const fx4* __restrict__ x0 = (const fx4*)(x + (size_t)row0 * E_);
    fx4* __restrict__ o0 = (fx4*)(outN + (size_t)row0 * E_);

    // 4 independent full-row loads (each 1 KB contiguous per instruction)
    fx4 a0 = x0[l];
    fx4 a1 = x0[l + 64];
    fx4 a2 = x0[l + 128];
    fx4 a3 = x0[l + 192];

    float r0 = 1.0f / fmaxf(sqrtf(sqsum[row0]),     EPS_NORM);
    float r1 = 1.0f / fmaxf(sqrtf(sqsum[row0 + 1]), EPS_NORM);
    float r2 = 1.0f / fmaxf(sqrtf(sqsum[row0 + 2]), EPS_NORM);
    float r3 = 1.0f / fmaxf(sqrtf(sqsum[row0 + 3]), EPS_NORM);

    __builtin_nontemporal_store(a0 * r0, &o0[l]);
    __builtin_nontemporal_store(a1 * r1, &o0[l + 64]);
    __builtin_nontemporal_store(a2 * r2, &o0[l + 128]);
    __builtin_nontemporal_store(a3 * r3, &o0[l + 192]);
}

// ---------------- kernel 2: loss -------------------------------------------
// 128 blocks x 256 threads; block handles rows [256b, 256b+256).
// Fast path: PBtgt[i]==i>>1 for all i  =>  s[k]=PBsum[2k]+PBsum[2k+1], n=32.
// Slow path: rebuild full histogram from rowsum/tgt with LDS atomics.
__global__ __launch_bounds__(256) void loss_kernel(
        const float* __restrict__ rowsum, const float* __restrict__ sqsum,
        const int* __restrict__ tgt,
        const float* __restrict__ PBsum, const int* __restrict__ PBtgt,
        const float* __restrict__ wP, const float* __restrict__ bP,
        float* __restrict__ outL) {
    __shared__ float s_h[S_];
    __shared__ float c_h[S_];
    __shared__ int   ired[256];
    __shared__ float fred[256];

    int tid = threadIdx.x;

    int packed = 0;     // (npos<<16) | nneg
    int bad = 0;
    #pragma unroll
    for (int j = 0; j < 4; ++j) {
        int k = tid * 4 + j;
        float sk = PBsum[2*k] + PBsum[2*k+1];
        int ok = (PBtgt[2*k] == k) & (PBtgt[2*k+1] == k);
        bad |= !ok;
        s_h[k] = sk;
        c_h[k] = 32.0f;
        float cv = sk * (1.0f / 32.0f);
        if (fabsf(cv) * 16.0f >= EPS_COS) packed += (cv > 0.f) ? (1 << 16) : 1;
    }
    ired[tid] = packed | (bad ? (1 << 15) : 0);   // bit15 = bad flag
    __syncthreads();
    #pragma unroll
    for (int st = 128; st > 0; st >>= 1) {
        if (tid < st) {
            int a = ired[tid], b = ired[tid + st];
            ired[tid] = ((a + b) & ~(1 << 15)) | ((a | b) & (1 << 15));
        }
        __syncthreads();
    }
    int agg  = ired[0];
    int slow = (agg >> 15) & 1;
    int npos = (agg >> 16) & 0xFFFF;
    int nneg = agg & 0x7FFF;

    if (slow) {   // ---- general path: rebuild histogram from rows ----
        __syncthreads();
        s_h[tid] = 0.f; s_h[tid + 256] = 0.f; s_h[tid + 512] = 0.f; s_h[tid + 768] = 0.f;
        c_h[tid] = 0.f; c_h[tid + 256] = 0.f; c_h[tid + 512] = 0.f; c_h[tid + 768] = 0.f;
        __syncthreads();
        for (int i = tid; i < B_; i += 256) {
            int t = tgt[i];
            atomicAdd(&s_h[t], rowsum[i]);
            atomicAdd(&c_h[t], 1.0f);
        }
        __syncthreads();
        packed = 0;
        #pragma unroll
        for (int j = 0; j < 4; ++j) {
            int k = tid * 4 + j;
            float cv = s_h[k] / c_h[k];
            if (fabsf(cv) * 16.0f >= EPS_COS) packed += (cv > 0.f) ? (1 << 16) : 1;
        }
        ired[tid] = packed;
        __syncthreads();
        #pragma unroll
        for (int st = 128; st > 0; st >>= 1) {
            if (tid < st) ired[tid] += ired[tid + st];
            __syncthreads();
        }
        npos = ired[0] >> 16;
        nneg = ired[0] & 0xFFFF;
    }

    // ---- per-row loss ----
    int i = blockIdx.x * 256 + tid;
    float w  = wP[0], b = bP[0];
    float wr = fmaxf(w, 0.f);

    int   t  = tgt[i];
    float rs = rowsum[i], sq = sqsum[i];
    float sj = s_h[t], nj = c_h[t];

    float nem = fmaxf(sqrtf(sq), EPS_COS);

    float dot = (sj * rs - sq) / nj;
    float nc  = sqrtf((float)E_ * sj * sj - 2.f * sj * rs + sq) / nj;
    float self_cos = dot / (nem * fmaxf(nc, EPS_COS));
    float self_sim = wr * self_cos + b;

    float A  = wr * rs / (nem * 16.0f);
    float xp =  A + b, xm = -A + b, xz = b;

    float ct = sj / nj;
    int np = npos, nm = nneg, nz = S_ - npos - nneg;
    if (fabsf(ct) * 16.0f >= EPS_COS) { if (ct > 0.f) np--; else nm--; }
    else nz--;

    float m = self_sim;
    if (np > 0) m = fmaxf(m, xp);
    if (nm > 0) m = fmaxf(m, xm);
    if (nz > 0) m = fmaxf(m, xz);
    float ssum = expf(self_sim - m)
               + (float)np * expf(xp - m)
               + (float)nm * expf(xm - m)
               + (float)nz * expf(xz - m);
    float contrib = m + logf(ssum) - self_sim;

    fred[tid] = contrib;
    __syncthreads();
    #pragma unroll
    for (int st = 128; st > 0; st >>= 1) {
        if (tid < st) fred[tid] += fred[tid + st];
        __syncthreads();
    }
    if (tid == 0) atomicAdd(outL, fred[0]);
}

extern "C" void kernel_launch(void* const* d_in, const int* in_sizes, int n_in,
                              void* d_out, int out_size, void* d_ws, size_t ws_size,
                              hipStream_t stream) {
    const float* inputs  = (const float*)d_in[0];
    const int*   targets = (const int*)d_in[1];
    const float* wP      = (const float*)d_in[2];
    const float* bP      = (const float*)d_in[3];
    float* outN = (float*)d_out;                    // [B,E] normalized
    float* outL = (float*)d_out + (size_t)B_ * E_;  // [1] loss

    float* wsf    = (float*)d_ws;
    float* rowsum = wsf;                     // B
    float* sqsum  = wsf + B_;                // B
    float* PBsum  = wsf + 2 * B_;            // 2048
    int*   PBtgt  = (int*)(PBsum + 2048);    // 2048

    reduce_kernel<<<B_ / 16, 256, 0, stream>>>(inputs, targets, outL,
                                               rowsum, sqsum, PBsum, PBtgt);
    scale_kernel<<<B_ / 16, 256, 0, stream>>>(inputs, sqsum, outN);
    loss_kernel<<<B_ / 256, 256, 0, stream>>>(rowsum, sqsum, targets,
                                              PBsum, PBtgt, wP, bP, outL);
}

// Round 14
// 19.140 us; speedup vs baseline: 1.2284x; 1.2284x over previous
//
#include <hip/hip_runtime.h>
#include <math.h>

#define B_ 32768
#define E_ 256
#define S_ 1024
#define EPS_COS 1e-8f
#define EPS_NORM 1e-12f

typedef float fx4 __attribute__((ext_vector_type(4)));

// ---------------- kernel 1: rows (streamed, 2-row pipelined) ---------------
// 1024 blocks x 256 threads, 32 rows/block: 16-lane group g owns rows
// {32b+2g, 32b+2g+1}. 8 loads issued up front; row-A butterfly + NT stores
// overlap row-B load returns (compiler pipelines via partial vmcnt).
// Per-block partial (sum over 32 rows, uniform target or -1) -> PB[b].
__global__ __launch_bounds__(256) void rows_kernel(
        const float* __restrict__ x, const int* __restrict__ tgt,
        float* __restrict__ outN, float* __restrict__ outL,
        float* __restrict__ rowsum, float* __restrict__ sqsum,
        float* __restrict__ PBsum, int* __restrict__ PBtgt) {
    __shared__ float sSum[32];
    __shared__ int   sTgt[32];

    int tid  = threadIdx.x;
    int g    = tid >> 4;                 // 16 groups of 16 lanes
    int li   = tid & 15;
    int rowA = blockIdx.x * 32 + g * 2;
    int rowB = rowA + 1;

    if (blockIdx.x == 0 && tid == 0) outL[0] = 0.f;

    const fx4* __restrict__ xa = (const fx4*)(x + (size_t)rowA * E_);
    const fx4* __restrict__ xb = (const fx4*)(x + (size_t)rowB * E_);
    fx4* __restrict__ oa = (fx4*)(outN + (size_t)rowA * E_);
    fx4* __restrict__ ob = (fx4*)(outN + (size_t)rowB * E_);

    // 8 loads in flight
    fx4 a0 = xa[li];
    fx4 a1 = xa[li + 16];
    fx4 a2 = xa[li + 32];
    fx4 a3 = xa[li + 48];
    fx4 b0 = xb[li];
    fx4 b1 = xb[li + 16];
    fx4 b2 = xb[li + 32];
    fx4 b3 = xb[li + 48];

    // ---- row A: reduce + store (overlaps row-B load returns) ----
    float sumA = (a0.x + a0.y + a0.z + a0.w) + (a1.x + a1.y + a1.z + a1.w)
               + (a2.x + a2.y + a2.z + a2.w) + (a3.x + a3.y + a3.z + a3.w);
    float sqA  = (a0.x*a0.x + a0.y*a0.y + a0.z*a0.z + a0.w*a0.w)
               + (a1.x*a1.x + a1.y*a1.y + a1.z*a1.z + a1.w*a1.w)
               + (a2.x*a2.x + a2.y*a2.y + a2.z*a2.z + a2.w*a2.w)
               + (a3.x*a3.x + a3.y*a3.y + a3.z*a3.z + a3.w*a3.w);
    #pragma unroll
    for (int o = 8; o >= 1; o >>= 1) {
        sumA += __shfl_xor(sumA, o, 64);
        sqA  += __shfl_xor(sqA,  o, 64);
    }
    float rnA = 1.0f / fmaxf(sqrtf(sqA), EPS_NORM);
    __builtin_nontemporal_store(a0 * rnA, &oa[li]);
    __builtin_nontemporal_store(a1 * rnA, &oa[li + 16]);
    __builtin_nontemporal_store(a2 * rnA, &oa[li + 32]);
    __builtin_nontemporal_store(a3 * rnA, &oa[li + 48]);

    // ---- row B ----
    float sumB = (b0.x + b0.y + b0.z + b0.w) + (b1.x + b1.y + b1.z + b1.w)
               + (b2.x + b2.y + b2.z + b2.w) + (b3.x + b3.y + b3.z + b3.w);
    float sqB  = (b0.x*b0.x + b0.y*b0.y + b0.z*b0.z + b0.w*b0.w)
               + (b1.x*b1.x + b1.y*b1.y + b1.z*b1.z + b1.w*b1.w)
               + (b2.x*b2.x + b2.y*b2.y + b2.z*b2.z + b2.w*b2.w)
               + (b3.x*b3.x + b3.y*b3.y + b3.z*b3.z + b3.w*b3.w);
    #pragma unroll
    for (int o = 8; o >= 1; o >>= 1) {
        sumB += __shfl_xor(sumB, o, 64);
        sqB  += __shfl_xor(sqB,  o, 64);
    }
    float rnB = 1.0f / fmaxf(sqrtf(sqB), EPS_NORM);
    __builtin_nontemporal_store(b0 * rnB, &ob[li]);
    __builtin_nontemporal_store(b1 * rnB, &ob[li + 16]);
    __builtin_nontemporal_store(b2 * rnB, &ob[li + 32]);
    __builtin_nontemporal_store(b3 * rnB, &ob[li + 48]);

    if (li == 0) {
        rowsum[rowA] = sumA;  sqsum[rowA] = sqA;
        rowsum[rowB] = sumB;  sqsum[rowB] = sqB;
        sSum[2*g]   = sumA;   sTgt[2*g]   = tgt[rowA];
        sSum[2*g+1] = sumB;   sTgt[2*g+1] = tgt[rowB];
    }
    __syncthreads();
    if (tid < 32) {                      // width-32 wave reduce
        float v = sSum[tid];
        int   t = sTgt[tid];
        int tmn = t, tmx = t;
        float tot = v;
        #pragma unroll
        for (int o = 16; o >= 1; o >>= 1) {
            tot += __shfl_xor(tot, o, 32);
            tmn  = min(tmn, __shfl_xor(tmn, o, 32));
            tmx  = max(tmx, __shfl_xor(tmx, o, 32));
        }
        if (tid == 0) {
            PBsum[blockIdx.x] = tot;
            PBtgt[blockIdx.x] = (tmn == tmx) ? tmn : -1;
        }
    }
}

// ---------------- kernel 2: loss -------------------------------------------
// 128 blocks x 256 threads; block handles rows [256b, 256b+256).
// Fast path: PBtgt[k]==k for all k  =>  s[k]=PBsum[k], n[k]=32.
// Slow path: rebuild full histogram from rowsum/tgt with LDS atomics.
__global__ __launch_bounds__(256) void loss_kernel(
        const float* __restrict__ rowsum, const float* __restrict__ sqsum,
        const int* __restrict__ tgt,
        const float* __restrict__ PBsum, const int* __restrict__ PBtgt,
        const float* __restrict__ wP, const float* __restrict__ bP,
        float* __restrict__ outL) {
    __shared__ float s_h[S_];
    __shared__ float c_h[S_];
    __shared__ int   ired[256];
    __shared__ float fred[256];

    int tid = threadIdx.x;

    int packed = 0;     // (npos<<16) | nneg
    int bad = 0;
    #pragma unroll
    for (int j = 0; j < 4; ++j) {
        int k = tid * 4 + j;
        float sk = PBsum[k];
        bad |= (PBtgt[k] != k);
        s_h[k] = sk;
        c_h[k] = 32.0f;
        float cv = sk * (1.0f / 32.0f);
        if (fabsf(cv) * 16.0f >= EPS_COS) packed += (cv > 0.f) ? (1 << 16) : 1;
    }
    ired[tid] = packed | (bad ? (1 << 15) : 0);   // bit15 = bad flag
    __syncthreads();
    #pragma unroll
    for (int st = 128; st > 0; st >>= 1) {
        if (tid < st) {
            int a = ired[tid], b = ired[tid + st];
            ired[tid] = ((a + b) & ~(1 << 15)) | ((a | b) & (1 << 15));
        }
        __syncthreads();
    }
    int agg  = ired[0];
    int slow = (agg >> 15) & 1;
    int npos = (agg >> 16) & 0xFFFF;
    int nneg = agg & 0x7FFF;

    if (slow) {   // ---- general path: rebuild histogram from rows ----
        __syncthreads();
        s_h[tid] = 0.f; s_h[tid + 256] = 0.f; s_h[tid + 512] = 0.f; s_h[tid + 768] = 0.f;
        c_h[tid] = 0.f; c_h[tid + 256] = 0.f; c_h[tid + 512] = 0.f; c_h[tid + 768] = 0.f;
        __syncthreads();
        for (int i = tid; i < B_; i += 256) {
            int t = tgt[i];
            atomicAdd(&s_h[t], rowsum[i]);
            atomicAdd(&c_h[t], 1.0f);
        }
        __syncthreads();
        packed = 0;
        #pragma unroll
        for (int j = 0; j < 4; ++j) {
            int k = tid * 4 + j;
            float cv = s_h[k] / c_h[k];
            if (fabsf(cv) * 16.0f >= EPS_COS) packed += (cv > 0.f) ? (1 << 16) : 1;
        }
        ired[tid] = packed;
        __syncthreads();
        #pragma unroll
        for (int st = 128; st > 0; st >>= 1) {
            if (tid < st) ired[tid] += ired[tid + st];
            __syncthreads();
        }
        npos = ired[0] >> 16;
        nneg = ired[0] & 0xFFFF;
    }

    // ---- per-row loss ----
    int i = blockIdx.x * 256 + tid;
    float w  = wP[0], b = bP[0];
    float wr = fmaxf(w, 0.f);

    int   t  = tgt[i];
    float rs = rowsum[i], sq = sqsum[i];
    float sj = s_h[t], nj = c_h[t];

    float nem = fmaxf(sqrtf(sq), EPS_COS);

    float dot = (sj * rs - sq) / nj;
    float nc  = sqrtf((float)E_ * sj * sj - 2.f * sj * rs + sq) / nj;
    float self_cos = dot / (nem * fmaxf(nc, EPS_COS));
    float self_sim = wr * self_cos + b;

    float A  = wr * rs / (nem * 16.0f);
    float xp =  A + b, xm = -A + b, xz = b;

    float ct = sj / nj;
    int np = npos, nm = nneg, nz = S_ - npos - nneg;
    if (fabsf(ct) * 16.0f >= EPS_COS) { if (ct > 0.f) np--; else nm--; }
    else nz--;

    float m = self_sim;
    if (np > 0) m = fmaxf(m, xp);
    if (nm > 0) m = fmaxf(m, xm);
    if (nz > 0) m = fmaxf(m, xz);
    float ssum = expf(self_sim - m)
               + (float)np * expf(xp - m)
               + (float)nm * expf(xm - m)
               + (float)nz * expf(xz - m);
    float contrib = m + logf(ssum) - self_sim;

    fred[tid] = contrib;
    __syncthreads();
    #pragma unroll
    for (int st = 128; st > 0; st >>= 1) {
        if (tid < st) fred[tid] += fred[tid + st];
        __syncthreads();
    }
    if (tid == 0) atomicAdd(outL, fred[0]);
}

extern "C" void kernel_launch(void* const* d_in, const int* in_sizes, int n_in,
                              void* d_out, int out_size, void* d_ws, size_t ws_size,
                              hipStream_t stream) {
    const float* inputs  = (const float*)d_in[0];
    const int*   targets = (const int*)d_in[1];
    const float* wP      = (const float*)d_in[2];
    const float* bP      = (const float*)d_in[3];
    float* outN = (float*)d_out;                    // [B,E] normalized
    float* outL = (float*)d_out + (size_t)B_ * E_;  // [1] loss

    float* wsf    = (float*)d_ws;
    float* rowsum = wsf;                     // B
    float* sqsum  = wsf + B_;                // B
    float* PBsum  = wsf + 2 * B_;            // 1024
    int*   PBtgt  = (int*)(PBsum + 1024);    // 1024

    rows_kernel<<<B_ / 32, 256, 0, stream>>>(inputs, targets, outN, outL,
                                             rowsum, sqsum, PBsum, PBtgt);
    loss_kernel<<<B_ / 256, 256, 0, stream>>>(rowsum, sqsum, targets,
                                              PBsum, PBtgt, wP, bP, outL);
}